// Round 1
// baseline (798.196 us; speedup 1.0000x reference)
//
#include <hip/hip_runtime.h>
#include <hip/hip_bf16.h>
#include <math.h>

#define TOKENS 32768
#define DIM    2048
#define NEXP   64
#define TOPK   6

#define TB 64                    // tokens per block
#define QS 4                     // D-splits = waves per block
#define CK 16                    // d-elems per thread per chunk
#define CHUNK (QS * CK)          // 64 contiguous d per chunk
#define NCHUNK (DIM / CHUNK)     // 32

__global__ __launch_bounds__(256, 2)
void gate_kernel(const float* __restrict__ x,
                 const float* __restrict__ w,
                 const float* __restrict__ bias,
                 float* __restrict__ out)
{
    // transposed x tile: xs[d][t], stride 65 -> bank (d+t)%32, conflict-free
    __shared__ float xs[CHUNK][TB + 1];
    // reduction buffer: red[t][e], stride 65 -> bank (t+e)%32, conflict-free
    __shared__ float red[TB][NEXP + 1];

    const int tid  = threadIdx.x;
    const int t    = tid & 63;                                    // token lane
    const int q    = __builtin_amdgcn_readfirstlane(tid >> 6);    // wave id (scalar!)
    const int tok0 = blockIdx.x * TB;

    // staging assignment: 16 threads per row, 16 rows per pass, 4 passes
    const int srow = tid >> 4;          // 0..15
    const int scol = (tid & 15) * 4;    // 0..60 step 4

    float acc[NEXP];
#pragma unroll
    for (int e = 0; e < NEXP; ++e) acc[e] = 0.f;

    // prefetch chunk 0 into registers (coalesced float4)
    float4 stg[4];
    {
        const float* base = x + (long)tok0 * DIM;
#pragma unroll
        for (int m = 0; m < 4; ++m) {
            int r = m * 16 + srow;
            stg[m] = *(const float4*)(base + (long)r * DIM + scol);
        }
    }

    for (int c = 0; c < NCHUNK; ++c) {
        // spill staged chunk c into LDS (transposed; 2-way banks max -> free)
#pragma unroll
        for (int m = 0; m < 4; ++m) {
            int r = m * 16 + srow;
            xs[scol + 0][r] = stg[m].x;
            xs[scol + 1][r] = stg[m].y;
            xs[scol + 2][r] = stg[m].z;
            xs[scol + 3][r] = stg[m].w;
        }
        __syncthreads();

        // prefetch chunk c+1 (hidden behind the 2048-cycle FMA block below)
        if (c + 1 < NCHUNK) {
            const float* base = x + (long)tok0 * DIM + (c + 1) * CHUNK;
#pragma unroll
            for (int m = 0; m < 4; ++m) {
                int r = m * 16 + srow;
                stg[m] = *(const float4*)(base + (long)r * DIM + scol);
            }
        }

        // pull my 16 x values: lane t reads xs[q*16+k][t] -> ds_read_b32, no conflicts
        float xv[CK];
#pragma unroll
        for (int k = 0; k < CK; ++k) xv[k] = xs[q * CK + k][t];

        // 64 experts x 16 FMAs; W address is wave-uniform -> s_load + SGPR-operand FMA
        const int dbase = c * CHUNK + q * CK;
#pragma unroll
        for (int e = 0; e < NEXP; ++e) {
            const float* wrow = w + (long)e * DIM + dbase;
#pragma unroll
            for (int k = 0; k < CK; ++k)
                acc[e] = fmaf(xv[k], wrow[k], acc[e]);
        }
        __syncthreads();
    }

    // ---- cross-wave reduction of D-quarter partials (deterministic order) ----
    if (q == 0) {
#pragma unroll
        for (int e = 0; e < NEXP; ++e) red[t][e] = acc[e];
    }
    __syncthreads();
    if (q == 1) {
#pragma unroll
        for (int e = 0; e < NEXP; ++e) red[t][e] += acc[e];
    }
    __syncthreads();
    if (q == 2) {
#pragma unroll
        for (int e = 0; e < NEXP; ++e) red[t][e] += acc[e];
    }
    __syncthreads();
    if (q == 3) {
#pragma unroll
        for (int e = 0; e < NEXP; ++e) red[t][e] += acc[e];
    }
    __syncthreads();

    // ---- epilogue: softmax + bias + top-6, one thread per token (wave 0) ----
    if (q == 0) {
        float lg[NEXP];
#pragma unroll
        for (int e = 0; e < NEXP; ++e) lg[e] = red[t][e];

        float mx = lg[0];
#pragma unroll
        for (int e = 1; e < NEXP; ++e) mx = fmaxf(mx, lg[e]);

        float sc[NEXP];
        float sum = 0.f;
#pragma unroll
        for (int e = 0; e < NEXP; ++e) { sc[e] = __expf(lg[e] - mx); sum += sc[e]; }
        const float inv = 1.0f / sum;

        float bz[NEXP];
#pragma unroll
        for (int e = 0; e < NEXP; ++e) {
            sc[e] *= inv;               // original softmax score (returned weight)
            bz[e] = sc[e] + bias[e];    // biased score (selection only)
        }

        const int tok = tok0 + t;
        float* wout = out + (long)tok * TOPK;
        float* iout = out + (long)TOKENS * TOPK + (long)tok * TOPK;

        int win[TOPK];
#pragma unroll
        for (int p = 0; p < TOPK; ++p) {
            float bmax = -INFINITY;
            int   best = 0;
            float bsc  = 0.f;
#pragma unroll
            for (int e = 0; e < NEXP; ++e) {
                bool skip = false;
#pragma unroll
                for (int pp = 0; pp < p; ++pp) skip = skip || (e == win[pp]);
                float v = skip ? -INFINITY : bz[e];
                if (v > bmax) { bmax = v; best = e; bsc = sc[e]; }  // strict > = lower-index tie-break (lax.top_k)
            }
            win[p] = best;
            wout[p] = bsc;            // ROUTE_SCALE == 1.0
            iout[p] = (float)best;    // indices stored as fp32 values
        }
    }
}

extern "C" void kernel_launch(void* const* d_in, const int* in_sizes, int n_in,
                              void* d_out, int out_size, void* d_ws, size_t ws_size,
                              hipStream_t stream) {
    const float* x  = (const float*)d_in[0];
    const float* w  = (const float*)d_in[1];
    const float* b  = (const float*)d_in[2];
    float* out = (float*)d_out;

    dim3 grid(TOKENS / TB);   // 512 blocks
    dim3 block(256);
    gate_kernel<<<grid, block, 0, stream>>>(x, w, b, out);
}

// Round 2
// 403.327 us; speedup vs baseline: 1.9790x; 1.9790x over previous
//
#include <hip/hip_runtime.h>
#include <hip/hip_bf16.h>
#include <math.h>

#define TOKENS 32768
#define DIM    2048
#define NEXP   64
#define TOPK   6

#define BM  128                 // tokens per block
#define BK  32                  // k-chunk
#define NIT (DIM / BK)          // 64 iterations
#define BMP 132                 // xs row stride (pad keeps 16B align + bank spread)
#define BEP 68                  // ws/red row stride

// smem float layout: [xs buf0 | xs buf1 | ws buf0 | ws buf1], red overlays front
#define XS_SZ (BK * BMP)        // 4224
#define WS_OFF (2 * XS_SZ)      // 8448
#define WS_SZ (BK * BEP)        // 2176
#define SMEM_FLOATS (2 * XS_SZ + 2 * WS_SZ)   // 12800 floats = 51.2 KB

__global__ __launch_bounds__(512, 2)
void gate_kernel(const float* __restrict__ x,
                 const float* __restrict__ w,
                 const float* __restrict__ bias,
                 float* __restrict__ out)
{
    __shared__ float smem[SMEM_FLOATS];

    const int tid  = threadIdx.x;
    const int tx   = tid & 15;      // expert group: experts tx*4..+3
    const int ty   = tid >> 4;      // token group: tokens ty*4..+3
    const int tok0 = blockIdx.x * BM;

    // staging: sr = row/expert 0..63, sc = float4 column over BK
    const int sr = tid >> 3;
    const int sc = tid & 7;

    float acc[4][4];
#pragma unroll
    for (int i = 0; i < 4; ++i)
#pragma unroll
        for (int j = 0; j < 4; ++j) acc[i][j] = 0.f;

    const float* xrow0 = x + (long)(tok0 + sr) * DIM + sc * 4;
    const float* xrow1 = x + (long)(tok0 + sr + 64) * DIM + sc * 4;
    const float* wrow  = w + (long)sr * DIM + sc * 4;

    // ---- prolog: stage tile 0 into buf 0 ----
    {
        float4 xa = *(const float4*)(xrow0);
        float4 xb = *(const float4*)(xrow1);
        float4 wv = *(const float4*)(wrow);
        float* xs = smem;                 // buf 0
        float* ws = smem + WS_OFF;        // buf 0
#pragma unroll
        for (int j = 0; j < 4; ++j) {
            xs[(sc * 4 + j) * BMP + sr]      = ((const float*)&xa)[j];
            xs[(sc * 4 + j) * BMP + sr + 64] = ((const float*)&xb)[j];
            ws[(sc * 4 + j) * BEP + sr]      = ((const float*)&wv)[j];
        }
    }
    __syncthreads();

    for (int it = 0; it < NIT; ++it) {
        const int buf = it & 1;
        const float* xs = smem + buf * XS_SZ;
        const float* ws = smem + WS_OFF + buf * WS_SZ;

        // issue global prefetch for tile it+1 early (consumed after compute)
        float4 xa, xb, wv;
        const bool more = (it + 1 < NIT);
        if (more) {
            const int k0 = (it + 1) * BK;
            xa = *(const float4*)(xrow0 + k0);
            xb = *(const float4*)(xrow1 + k0);
            wv = *(const float4*)(wrow  + k0);
        }

        // compute: 32 k-steps, 16 FMAs each
#pragma unroll
        for (int k = 0; k < BK; ++k) {
            const float4 a = *(const float4*)(xs + k * BMP + ty * 4);
            const float4 b = *(const float4*)(ws + k * BEP + tx * 4);
#pragma unroll
            for (int i = 0; i < 4; ++i) {
#pragma unroll
                for (int j = 0; j < 4; ++j)
                    acc[i][j] = fmaf(((const float*)&a)[i],
                                     ((const float*)&b)[j], acc[i][j]);
            }
        }

        if (more) {
            float* nxs = smem + (buf ^ 1) * XS_SZ;
            float* nws = smem + WS_OFF + (buf ^ 1) * WS_SZ;
#pragma unroll
            for (int j = 0; j < 4; ++j) {
                nxs[(sc * 4 + j) * BMP + sr]      = ((const float*)&xa)[j];
                nxs[(sc * 4 + j) * BMP + sr + 64] = ((const float*)&xb)[j];
                nws[(sc * 4 + j) * BEP + sr]      = ((const float*)&wv)[j];
            }
        }
        __syncthreads();
    }

    // ---- dump accumulators to red[m][e] (overlays xs/ws region) ----
    float* red = smem;   // stride BEP, 128 x 68 = 8704 floats < 12800
#pragma unroll
    for (int i = 0; i < 4; ++i)
#pragma unroll
        for (int j = 0; j < 4; ++j)
            red[(ty * 4 + i) * BEP + (tx * 4 + j)] = acc[i][j];
    __syncthreads();

    // ---- epilogue: one thread per token (threads 0..127) ----
    if (tid < BM) {
        const int m = tid;
        float lg[NEXP];
#pragma unroll
        for (int e = 0; e < NEXP; ++e) lg[e] = red[m * BEP + e];

        float mx = lg[0];
#pragma unroll
        for (int e = 1; e < NEXP; ++e) mx = fmaxf(mx, lg[e]);

        float sc4[NEXP];
        float sum = 0.f;
#pragma unroll
        for (int e = 0; e < NEXP; ++e) { sc4[e] = __expf(lg[e] - mx); sum += sc4[e]; }
        const float inv = 1.0f / sum;

        float bz[NEXP];
#pragma unroll
        for (int e = 0; e < NEXP; ++e) {
            sc4[e] *= inv;               // original softmax score (returned weight)
            bz[e]  = sc4[e] + bias[e];   // biased score (selection only)
        }

        const int tok = tok0 + m;
        float* wout = out + (long)tok * TOPK;
        float* iout = out + (long)TOKENS * TOPK + (long)tok * TOPK;

        int win[TOPK];
#pragma unroll
        for (int p = 0; p < TOPK; ++p) {
            float bmax = -INFINITY;
            int   best = 0;
            float bsc  = 0.f;
#pragma unroll
            for (int e = 0; e < NEXP; ++e) {
                bool skip = false;
#pragma unroll
                for (int pp = 0; pp < p; ++pp) skip = skip || (e == win[pp]);
                float v = skip ? -INFINITY : bz[e];
                if (v > bmax) { bmax = v; best = e; bsc = sc4[e]; } // strict > = lower-index tie-break
            }
            win[p]  = best;
            wout[p] = bsc;              // ROUTE_SCALE == 1.0
            iout[p] = (float)best;      // indices as fp32 values
        }
    }
}

extern "C" void kernel_launch(void* const* d_in, const int* in_sizes, int n_in,
                              void* d_out, int out_size, void* d_ws, size_t ws_size,
                              hipStream_t stream) {
    const float* x = (const float*)d_in[0];
    const float* w = (const float*)d_in[1];
    const float* b = (const float*)d_in[2];
    float* out = (float*)d_out;

    dim3 grid(TOKENS / BM);   // 256 blocks -> 1 per CU
    dim3 block(512);          // 8 waves
    gate_kernel<<<grid, block, 0, stream>>>(x, w, b, out);
}

// Round 4
// 386.153 us; speedup vs baseline: 2.0670x; 1.0445x over previous
//
#include <hip/hip_runtime.h>
#include <hip/hip_bf16.h>
#include <math.h>

#define TOKENS 32768
#define DIM    2048
#define NEXP   64
#define TOPK   6

#define BM   64                // tokens per block
#define BK   64                // fp32 k per staged chunk
#define NIT  (DIM / BK)        // 32 chunks
#define ST   72                // bf16 elems per LDS row (144 B: 16B-aligned, 2-way banks)
#define PLANE (BM * ST)        // 4608 bf16 elems per plane

typedef float f32x4 __attribute__((ext_vector_type(4)));
typedef short sh8  __attribute__((ext_vector_type(8)));

__device__ __forceinline__ ushort f2bf(float f) {
    union { __hip_bfloat16 b; ushort u; } c;
    c.b = __float2bfloat16(f);
    return c.u;
}
__device__ __forceinline__ float bf2f(ushort u) {
    union { ushort u; __hip_bfloat16 b; } c;
    c.u = u;
    return __bfloat162float(c.b);
}

__global__ __launch_bounds__(256, 2)
void gate_kernel(const float* __restrict__ x,
                 const float* __restrict__ w,
                 const float* __restrict__ bias,
                 float* __restrict__ out)
{
    // planes: 0=XH 1=XM 2=XL 3=WH 4=WM 5=WL ; 6*4608*2 = 55296 B
    __shared__ __align__(16) short smem[6 * PLANE];

    const int tid  = threadIdx.x;
    const int wave = tid >> 6;
    const int lane = tid & 63;
    const int quad = lane >> 4;
    const int l15  = lane & 15;
    const int tok0 = blockIdx.x * BM;

    // staging: 4 threads per row, 16 contiguous floats each
    const int sr = tid >> 2;         // row 0..63 (token row for x, expert row for w)
    const int sq = tid & 3;          // 16-float segment

    const float* xg = x + (long)(tok0 + sr) * DIM + sq * 16;
    const float* wg = w + (long)sr * DIM + sq * 16;

    f32x4 acc[4];
#pragma unroll
    for (int nt = 0; nt < 4; ++nt) acc[nt] = (f32x4){0.f, 0.f, 0.f, 0.f};

    float4 xf[4], wf[4];

    // exact 3-way bf16 split: f == h + m + l exactly (9+9+6 mantissa bits >= 24)
    auto stage = [&]() {
        const int base = sr * ST + sq * 16;
#pragma unroll
        for (int g = 0; g < 2; ++g) {
            sh8 xh, xm, xl, wh, wm, wl;
#pragma unroll
            for (int i = 0; i < 8; ++i) {
                {
                    float f = ((const float*)&xf[g * 2])[i];
                    ushort h = f2bf(f);  float r1 = f - bf2f(h);
                    ushort m = f2bf(r1); float r2 = r1 - bf2f(m);
                    ushort l = f2bf(r2);
                    xh[i] = (short)h; xm[i] = (short)m; xl[i] = (short)l;
                }
                {
                    float f = ((const float*)&wf[g * 2])[i];
                    ushort h = f2bf(f);  float r1 = f - bf2f(h);
                    ushort m = f2bf(r1); float r2 = r1 - bf2f(m);
                    ushort l = f2bf(r2);
                    wh[i] = (short)h; wm[i] = (short)m; wl[i] = (short)l;
                }
            }
            *(sh8*)&smem[0 * PLANE + base + g * 8] = xh;
            *(sh8*)&smem[1 * PLANE + base + g * 8] = xm;
            *(sh8*)&smem[2 * PLANE + base + g * 8] = xl;
            *(sh8*)&smem[3 * PLANE + base + g * 8] = wh;
            *(sh8*)&smem[4 * PLANE + base + g * 8] = wm;
            *(sh8*)&smem[5 * PLANE + base + g * 8] = wl;
        }
    };

    // prolog: load chunk 0
#pragma unroll
    for (int j = 0; j < 4; ++j) {
        xf[j] = *(const float4*)(xg + j * 4);
        wf[j] = *(const float4*)(wg + j * 4);
    }

    for (int it = 0; it < NIT; ++it) {
        stage();
        __syncthreads();

        // prefetch next chunk into regs (consumed by next stage(); hidden behind MFMAs)
        if (it + 1 < NIT) {
            const int k0 = (it + 1) * BK;
#pragma unroll
            for (int j = 0; j < 4; ++j) {
                xf[j] = *(const float4*)(xg + k0 + j * 4);
                wf[j] = *(const float4*)(wg + k0 + j * 4);
            }
        }

        // compute: wave owns tokens [wave*16, wave*16+16) x all 64 experts
        const int arow = (wave * 16 + l15) * ST;
#pragma unroll
        for (int ks = 0; ks < 2; ++ks) {
            const int kof = ks * 32 + quad * 8;
            sh8 ah = *(const sh8*)&smem[0 * PLANE + arow + kof];
            sh8 am = *(const sh8*)&smem[1 * PLANE + arow + kof];
            sh8 al = *(const sh8*)&smem[2 * PLANE + arow + kof];
#pragma unroll
            for (int nt = 0; nt < 4; ++nt) {
                const int brow = (nt * 16 + l15) * ST;
                sh8 bh = *(const sh8*)&smem[3 * PLANE + brow + kof];
                sh8 bm = *(const sh8*)&smem[4 * PLANE + brow + kof];
                sh8 bl = *(const sh8*)&smem[5 * PLANE + brow + kof];
                acc[nt] = __builtin_amdgcn_mfma_f32_16x16x32_bf16(ah, bh, acc[nt], 0, 0, 0); // hh
                acc[nt] = __builtin_amdgcn_mfma_f32_16x16x32_bf16(am, bh, acc[nt], 0, 0, 0); // mh
                acc[nt] = __builtin_amdgcn_mfma_f32_16x16x32_bf16(ah, bm, acc[nt], 0, 0, 0); // hm
                acc[nt] = __builtin_amdgcn_mfma_f32_16x16x32_bf16(al, bh, acc[nt], 0, 0, 0); // lh
                acc[nt] = __builtin_amdgcn_mfma_f32_16x16x32_bf16(am, bm, acc[nt], 0, 0, 0); // mm
                acc[nt] = __builtin_amdgcn_mfma_f32_16x16x32_bf16(ah, bl, acc[nt], 0, 0, 0); // hl
            }
        }
        __syncthreads();   // protect LDS before next stage() overwrite
    }

    // ---- logits -> red LDS (stride 69: odd -> conflict-free scalar access) ----
    float* red = (float*)smem;   // 64 x 69 floats = 17.7 KB, overlays staging planes
#pragma unroll
    for (int nt = 0; nt < 4; ++nt)
#pragma unroll
        for (int j = 0; j < 4; ++j) {
            const int row = wave * 16 + quad * 4 + j;   // token (C/D row = quad*4+reg)
            const int col = nt * 16 + l15;              // expert (C/D col = lane&15)
            red[row * 69 + col] = acc[nt][j];
        }
    __syncthreads();

    // ---- epilogue: softmax + bias + top-6, one thread per token ----
    if (tid < BM) {
        const int m = tid;
        float lg[NEXP];
#pragma unroll
        for (int e = 0; e < NEXP; ++e) lg[e] = red[m * 69 + e];

        float mx = lg[0];
#pragma unroll
        for (int e = 1; e < NEXP; ++e) mx = fmaxf(mx, lg[e]);

        float sc4[NEXP];
        float sum = 0.f;
#pragma unroll
        for (int e = 0; e < NEXP; ++e) { sc4[e] = __expf(lg[e] - mx); sum += sc4[e]; }
        const float inv = 1.0f / sum;

        float bz[NEXP];
#pragma unroll
        for (int e = 0; e < NEXP; ++e) {
            sc4[e] *= inv;               // original softmax score (returned weight)
            bz[e]  = sc4[e] + bias[e];   // biased score (selection only)
        }

        const int tok = tok0 + m;
        float* wout = out + (long)tok * TOPK;
        float* iout = out + (long)TOKENS * TOPK + (long)tok * TOPK;

        int win[TOPK];
#pragma unroll
        for (int p = 0; p < TOPK; ++p) {
            float bmax = -INFINITY;
            int   best = 0;
            float bsc  = 0.f;
#pragma unroll
            for (int e = 0; e < NEXP; ++e) {
                bool skip = false;
#pragma unroll
                for (int pp = 0; pp < p; ++pp) skip = skip || (e == win[pp]);
                float v = skip ? -INFINITY : bz[e];
                if (v > bmax) { bmax = v; best = e; bsc = sc4[e]; } // strict > = lower-index tie-break
            }
            win[p]  = best;
            wout[p] = bsc;              // ROUTE_SCALE == 1.0
            iout[p] = (float)best;      // indices as fp32 values
        }
    }
}

extern "C" void kernel_launch(void* const* d_in, const int* in_sizes, int n_in,
                              void* d_out, int out_size, void* d_ws, size_t ws_size,
                              hipStream_t stream) {
    const float* x = (const float*)d_in[0];
    const float* w = (const float*)d_in[1];
    const float* b = (const float*)d_in[2];
    float* out = (float*)d_out;

    dim3 grid(TOKENS / BM);   // 512 blocks -> 2 per CU
    dim3 block(256);          // 4 waves
    gate_kernel<<<grid, block, 0, stream>>>(x, w, b, out);
}